// Round 8
// baseline (469.491 us; speedup 1.0000x reference)
//
#include <hip/hip_runtime.h>

// AutoInt fused: embedding gather -> 2x MHSA (32 fields, 4 heads x 32) -> logit.
// R8: SPLIT embedding into its own streaming kernel (full occupancy, no MFMA)
//     writing y1 [8192][32][72] bf16 to ws; compute kernel (R6 structure) now
//     starts from a coalesced 4.6KB copy instead of ~45 HBM-latency gathers
//     serialized into low-occupancy MFMA waves. Fallback to fused if ws small.

#define NSAMP 8192
#define S_Y1 72    // y1 stride (shorts): 144B rows (16B-aligned)
#define S_Y2 136   // layer2 input stride (shorts): 272B rows
#define S_T 36     // per-head 32x32 tile stride (shorts): 72B rows (16B-aligned)
#define Y1WS_STRIDE 2304   // 32*72 shorts per sample in ws

typedef __attribute__((ext_vector_type(8))) short bf8_t;  // 8 bf16
typedef __attribute__((ext_vector_type(4))) float f4_t;   // 4 fp32

__device__ __forceinline__ short f2bf(float f) {
  unsigned u = __float_as_uint(f);
  u += 0x7fffu + ((u >> 16) & 1u);   // RNE
  return (short)(u >> 16);
}
__device__ __forceinline__ unsigned pack2(float a, float b) {
  return ((unsigned)(unsigned short)f2bf(a)) |
         (((unsigned)(unsigned short)f2bf(b)) << 16);
}
__device__ __forceinline__ float bf2f(short s) {
  return __uint_as_float(((unsigned)(unsigned short)s) << 16);
}
__device__ __forceinline__ f4_t mfma16(bf8_t a, bf8_t b, f4_t c) {
  return __builtin_amdgcn_mfma_f32_16x16x32_bf16(a, b, c, 0, 0, 0);
}

// acc[mi][ni] C-tile of: out[f][n0+n] = sum_d y[f][d]*W[n0+n][d] + b[n0+n]
template<int D_IN>
__device__ __forceinline__ void proj(const bf8_t (&af)[2][D_IN / 32],
                                     const short* __restrict__ W,
                                     const float* __restrict__ bias,
                                     int n0, int c, int quad, f4_t (&acc)[2][2]) {
  constexpr int KS = D_IN / 32;
#pragma unroll
  for (int ni = 0; ni < 2; ++ni) {
    float bb = bias[n0 + ni * 16 + c];
    bf8_t bfr[KS];
#pragma unroll
    for (int k = 0; k < KS; ++k)
      bfr[k] = *(const bf8_t*)&W[(n0 + ni * 16 + c) * D_IN + k * 32 + quad * 8];
#pragma unroll
    for (int mi = 0; mi < 2; ++mi) {
      f4_t a; a[0] = bb; a[1] = bb; a[2] = bb; a[3] = bb;
#pragma unroll
      for (int k = 0; k < KS; ++k) a = mfma16(af[mi][k], bfr[k], a);
      acc[mi][ni] = a;
    }
  }
}

// One attention layer for this wave's head (R6 structure, unchanged).
template<int D_IN, int S_IN, bool FUSE>
__device__ float attn_layer(const short* yIn, short* yOut,
                            const short* __restrict__ Wq, const short* __restrict__ Wk,
                            const short* __restrict__ Wv, const short* __restrict__ Wr,
                            const float* __restrict__ bq, const float* __restrict__ bk,
                            const float* __restrict__ bvp, const float* __restrict__ br,
                            short* bQ, short* bK, const short* __restrict__ lwT) {
  constexpr int KS = D_IN / 32;
  const int lane = threadIdx.x & 63;
  const int c = lane & 15;
  const int quad = lane >> 4;
  const int head = threadIdx.x >> 6;
  const int n0 = head * 32;

  bf8_t af[2][KS];
#pragma unroll
  for (int mi = 0; mi < 2; ++mi)
#pragma unroll
    for (int k = 0; k < KS; ++k)
      af[mi][k] = *(const bf8_t*)&yIn[(mi * 16 + c) * S_IN + k * 32 + quad * 8];
  __syncthreads();   // yIn (overlaid on scr) is now dead; scr writable

  f4_t acc[2][2];

  // ---- Q -> bQ
  proj<D_IN>(af, Wq, bq, n0, c, quad, acc);
#pragma unroll
  for (int mi = 0; mi < 2; ++mi)
#pragma unroll
    for (int ni = 0; ni < 2; ++ni)
#pragma unroll
      for (int r = 0; r < 4; ++r)
        bQ[(mi * 16 + quad * 4 + r) * S_T + ni * 16 + c] = f2bf(acc[mi][ni][r]);

  // ---- K -> bK
  proj<D_IN>(af, Wk, bk, n0, c, quad, acc);
#pragma unroll
  for (int mi = 0; mi < 2; ++mi)
#pragma unroll
    for (int ni = 0; ni < 2; ++ni)
#pragma unroll
      for (int r = 0; r < 4; ++r)
        bK[(mi * 16 + quad * 4 + r) * S_T + ni * 16 + c] = f2bf(acc[mi][ni][r]);

  // ---- Res -> registers
  f4_t res[2][2];
  proj<D_IN>(af, Wr, br, n0, c, quad, res);

  // ---- scores = Q K^T
  f4_t z[2][2];
#pragma unroll
  for (int mi = 0; mi < 2; ++mi) {
    bf8_t qa = *(const bf8_t*)&bQ[(mi * 16 + c) * S_T + quad * 8];
#pragma unroll
    for (int ni = 0; ni < 2; ++ni) {
      bf8_t kb = *(const bf8_t*)&bK[(ni * 16 + c) * S_T + quad * 8];
      f4_t zz; zz[0] = 0.f; zz[1] = 0.f; zz[2] = 0.f; zz[3] = 0.f;
      z[mi][ni] = mfma16(qa, kb, zz);
    }
  }

  // ---- e = exp(z) unnormalized -> bQ (scores O(1), no max-sub)
#pragma unroll
  for (int mi = 0; mi < 2; ++mi)
#pragma unroll
    for (int ni = 0; ni < 2; ++ni)
#pragma unroll
      for (int r = 0; r < 4; ++r)
        bQ[(mi * 16 + quad * 4 + r) * S_T + ni * 16 + c] = f2bf(__expf(z[mi][ni][r]));

  // ---- V -> bK transposed
  proj<D_IN>(af, Wv, bvp, n0, c, quad, acc);
#pragma unroll
  for (int mi = 0; mi < 2; ++mi)
#pragma unroll
    for (int ni = 0; ni < 2; ++ni) {
      short4 pk;
      pk.x = f2bf(acc[mi][ni][0]); pk.y = f2bf(acc[mi][ni][1]);
      pk.z = f2bf(acc[mi][ni][2]); pk.w = f2bf(acc[mi][ni][3]);
      *(short4*)&bK[(ni * 16 + c) * S_T + mi * 16 + quad * 4] = pk;
    }

  // ---- PV (unnormalized) + row-sums via all-ones B-frag
  const short onebf = (short)0x3F80;
  bf8_t ones = {onebf, onebf, onebf, onebf, onebf, onebf, onebf, onebf};
  f4_t pv[2][2], sums[2];
#pragma unroll
  for (int mi = 0; mi < 2; ++mi) {
    bf8_t pa = *(const bf8_t*)&bQ[(mi * 16 + c) * S_T + quad * 8];
    f4_t zz; zz[0] = 0.f; zz[1] = 0.f; zz[2] = 0.f; zz[3] = 0.f;
    sums[mi] = mfma16(pa, ones, zz);
#pragma unroll
    for (int ni = 0; ni < 2; ++ni) {
      bf8_t vb = *(const bf8_t*)&bK[(ni * 16 + c) * S_T + quad * 8];
      f4_t z2; z2[0] = 0.f; z2[1] = 0.f; z2[2] = 0.f; z2[3] = 0.f;
      pv[mi][ni] = mfma16(pa, vb, z2);
    }
  }
  float invs[2][4];
#pragma unroll
  for (int mi = 0; mi < 2; ++mi)
#pragma unroll
    for (int r = 0; r < 4; ++r) invs[mi][r] = 1.f / sums[mi][r];

  // ---- O = PV/s + Res, relu; store (layer1) or fuse logit dot (layer2)
  float p = 0.f;
  if (FUSE) {
#pragma unroll
    for (int mi = 0; mi < 2; ++mi)
#pragma unroll
      for (int ni = 0; ni < 2; ++ni) {
        short4 l4 = *(const short4*)&lwT[(n0 + ni * 16 + c) * 32 + mi * 16 + quad * 4];
        p += fmaxf(fmaf(pv[mi][ni][0], invs[mi][0], res[mi][ni][0]), 0.f) * bf2f(l4.x);
        p += fmaxf(fmaf(pv[mi][ni][1], invs[mi][1], res[mi][ni][1]), 0.f) * bf2f(l4.y);
        p += fmaxf(fmaf(pv[mi][ni][2], invs[mi][2], res[mi][ni][2]), 0.f) * bf2f(l4.z);
        p += fmaxf(fmaf(pv[mi][ni][3], invs[mi][3], res[mi][ni][3]), 0.f) * bf2f(l4.w);
      }
  } else {
    __syncthreads();
#pragma unroll
    for (int mi = 0; mi < 2; ++mi)
#pragma unroll
      for (int ni = 0; ni < 2; ++ni)
#pragma unroll
        for (int r = 0; r < 4; ++r)
          yOut[(mi * 16 + quad * 4 + r) * S_Y2 + n0 + ni * 16 + c] =
              f2bf(fmaxf(fmaf(pv[mi][ni][r], invs[mi][r], res[mi][ni][r]), 0.f));
  }
  return p;
}

// ---- streaming embedding kernel: one block per sample, writes y1 to ws ----
__global__ __launch_bounds__(256, 8) void embed_k(
    const int* __restrict__ onehot_i, const float* __restrict__ onehot_x,
    const int* __restrict__ mh_i, const float* __restrict__ mh_x,
    const float* __restrict__ ctns, const float* __restrict__ xx,
    const float* __restrict__ xy, short* __restrict__ y1ws) {
  const int s = blockIdx.x;
  const int t = threadIdx.x;
  short* y1 = &y1ws[(size_t)s * Y1WS_STRIDE];

  for (int idx = t; idx < 320; idx += 256) {     // 20 onehot x 16 float4
    int f = idx >> 4, e4 = idx & 15;
    int row = onehot_i[s * 20 + f];
    float xw = onehot_x[s * 20 + f];
    float4 xv = *(const float4*)&xx[row * 64 + e4 * 4];
    uint2 w; w.x = pack2(xv.x * xw, xv.y * xw); w.y = pack2(xv.z * xw, xv.w * xw);
    *(uint2*)&y1[f * S_Y1 + e4 * 4] = w;
  }
  {                                               // 2 multihot x 16 float4, 8-way k-split
    int slot = t >> 3, ks = t & 7;
    int j = slot >> 4, e4 = slot & 15;
    const int* ip = &mh_i[(j * NSAMP + s) * 50];
    const float* xp = &mh_x[(j * NSAMP + s) * 50];
    float a0 = 0.f, a1 = 0.f, a2 = 0.f, a3 = 0.f;
    for (int k = ks; k < 50; k += 8) {
      float4 xv = *(const float4*)&xx[ip[k] * 64 + e4 * 4];
      float w = xp[k];
      a0 += xv.x * w; a1 += xv.y * w; a2 += xv.z * w; a3 += xv.w * w;
    }
#pragma unroll
    for (int d = 1; d < 8; d <<= 1) {
      a0 += __shfl_xor(a0, d); a1 += __shfl_xor(a1, d);
      a2 += __shfl_xor(a2, d); a3 += __shfl_xor(a3, d);
    }
    if (ks == 0) {
      uint2 w; w.x = pack2(a0, a1); w.y = pack2(a2, a3);
      *(uint2*)&y1[(20 + j) * S_Y1 + e4 * 4] = w;
    }
  }
  if (t < 160) {                                  // 10 ctns x 16 float4
    int ci = t >> 4, e4 = t & 15;
    float cv = ctns[s * 10 + ci];
    float4 xv = *(const float4*)&xy[ci * 64 + e4 * 4];
    uint2 w; w.x = pack2(cv * xv.x, cv * xv.y); w.y = pack2(cv * xv.z, cv * xv.w);
    *(uint2*)&y1[(22 + ci) * S_Y1 + e4 * 4] = w;
  }
}

template<bool SPLIT>
__global__ __launch_bounds__(256, 4) void autoint_main(
    const int* __restrict__ onehot_i, const float* __restrict__ onehot_x,
    const int* __restrict__ mh_i, const float* __restrict__ mh_x,
    const float* __restrict__ ctns, const float* __restrict__ xx,
    const float* __restrict__ xy,
    const float* __restrict__ bq1, const float* __restrict__ bk1,
    const float* __restrict__ bv1, const float* __restrict__ br1,
    const float* __restrict__ bq2, const float* __restrict__ bk2,
    const float* __restrict__ bv2, const float* __restrict__ br2,
    const float* __restrict__ logitb, const short* __restrict__ wbf,
    const short* __restrict__ y1ws, float* __restrict__ out) {
  // scr union (18432 B) also hosts yA (4608 B) and yB (8704 B) at its base.
  __shared__ __align__(16) short scr[4][2][32 * S_T];
  __shared__ float red[4];

  const int s = blockIdx.x;
  const int t = threadIdx.x;
  const int head = t >> 6;
  short* bQ = scr[head][0];
  short* bK = scr[head][1];
  short* yA = &scr[0][0][0];

  if (SPLIT) {
    // ---- coalesced copy y1ws -> yA (4608 B = 288 uint4)
    const uint4* src = (const uint4*)&y1ws[(size_t)s * Y1WS_STRIDE];
    uint4* dst = (uint4*)yA;
    dst[t] = src[t];
    if (t < 32) dst[256 + t] = src[256 + t];
  } else {
    // ---- fused embedding build into yA (R6 path)
    for (int idx = t; idx < 320; idx += 256) {
      int f = idx >> 4, e4 = idx & 15;
      int row = onehot_i[s * 20 + f];
      float xw = onehot_x[s * 20 + f];
      float4 xv = *(const float4*)&xx[row * 64 + e4 * 4];
      uint2 w; w.x = pack2(xv.x * xw, xv.y * xw); w.y = pack2(xv.z * xw, xv.w * xw);
      *(uint2*)&yA[f * S_Y1 + e4 * 4] = w;
    }
    {
      int slot = t >> 3, ks = t & 7;
      int j = slot >> 4, e4 = slot & 15;
      const int* ip = &mh_i[(j * NSAMP + s) * 50];
      const float* xp = &mh_x[(j * NSAMP + s) * 50];
      float a0 = 0.f, a1 = 0.f, a2 = 0.f, a3 = 0.f;
      for (int k = ks; k < 50; k += 8) {
        float4 xv = *(const float4*)&xx[ip[k] * 64 + e4 * 4];
        float w = xp[k];
        a0 += xv.x * w; a1 += xv.y * w; a2 += xv.z * w; a3 += xv.w * w;
      }
#pragma unroll
      for (int d = 1; d < 8; d <<= 1) {
        a0 += __shfl_xor(a0, d); a1 += __shfl_xor(a1, d);
        a2 += __shfl_xor(a2, d); a3 += __shfl_xor(a3, d);
      }
      if (ks == 0) {
        uint2 w; w.x = pack2(a0, a1); w.y = pack2(a2, a3);
        *(uint2*)&yA[(20 + j) * S_Y1 + e4 * 4] = w;
      }
    }
    if (t < 160) {
      int ci = t >> 4, e4 = t & 15;
      float cv = ctns[s * 10 + ci];
      float4 xv = *(const float4*)&xy[ci * 64 + e4 * 4];
      uint2 w; w.x = pack2(cv * xv.x, cv * xv.y); w.y = pack2(cv * xv.z, cv * xv.w);
      *(uint2*)&yA[(22 + ci) * S_Y1 + e4 * 4] = w;
    }
  }
  __syncthreads();

  attn_layer<64, S_Y1, false>(yA, yA,
      wbf + 0, wbf + 8192, wbf + 16384, wbf + 24576,
      bq1, bk1, bv1, br1, bQ, bK, nullptr);
  __syncthreads();
  float p = attn_layer<128, S_Y2, true>(yA, nullptr,
      wbf + 32768, wbf + 49152, wbf + 65536, wbf + 81920,
      bq2, bk2, bv2, br2, bQ, bK, wbf + 98304);

#pragma unroll
  for (int off = 32; off > 0; off >>= 1) p += __shfl_xor(p, off);
  if ((t & 63) == 0) red[head] = p;
  __syncthreads();
  if (t == 0) {
    float zz = red[0] + red[1] + red[2] + red[3] + logitb[0];
    out[s] = 1.f / (1.f + __expf(-zz));
  }
}

// fp32 -> bf16 weight conversion into ws:
// [0)QW1 [8192)KW1 [16384)VW1 [24576)RW1 [32768)QW2 [49152)KW2 [65536)VW2
// [81920)RW2 [98304)logitW TRANSPOSED [128][32]
__global__ void convert_w(const float* __restrict__ qw1, const float* __restrict__ kw1,
                          const float* __restrict__ vw1, const float* __restrict__ rw1,
                          const float* __restrict__ qw2, const float* __restrict__ kw2,
                          const float* __restrict__ vw2, const float* __restrict__ rw2,
                          const float* __restrict__ lw, short* __restrict__ outw) {
  int i = blockIdx.x * 256 + threadIdx.x;
  if (i >= 102400) return;
  float v;
  if (i < 32768) {
    int tsel = i >> 13, j = i & 8191;
    const float* src = tsel == 0 ? qw1 : tsel == 1 ? kw1 : tsel == 2 ? vw1 : rw1;
    v = src[j];
  } else if (i < 98304) {
    int k = i - 32768;
    int tsel = k >> 14, j = k & 16383;
    const float* src = tsel == 0 ? qw2 : tsel == 1 ? kw2 : tsel == 2 ? vw2 : rw2;
    v = src[j];
  } else {
    int j = i - 98304;                 // outw layout: lwT[col*32+row]
    v = lw[(j & 31) * 128 + (j >> 5)];
  }
  outw[i] = f2bf(v);
}

extern "C" void kernel_launch(void* const* d_in, const int* in_sizes, int n_in,
                              void* d_out, int out_size, void* d_ws, size_t ws_size,
                              hipStream_t stream) {
  short* wbf = (short*)d_ws;                 // 204800 B weights
  short* y1ws = wbf + 102400;                // + 8192*2304*2 B = 37.75 MB
  const size_t need = 204800 + (size_t)NSAMP * Y1WS_STRIDE * 2;

  convert_w<<<400, 256, 0, stream>>>(
      (const float*)d_in[7], (const float*)d_in[9], (const float*)d_in[11],
      (const float*)d_in[13], (const float*)d_in[15], (const float*)d_in[17],
      (const float*)d_in[19], (const float*)d_in[21], (const float*)d_in[23], wbf);

  if (ws_size >= need) {
    embed_k<<<NSAMP, 256, 0, stream>>>(
        (const int*)d_in[0], (const float*)d_in[1], (const int*)d_in[2],
        (const float*)d_in[3], (const float*)d_in[4], (const float*)d_in[5],
        (const float*)d_in[6], y1ws);
    autoint_main<true><<<NSAMP, 256, 0, stream>>>(
        (const int*)d_in[0], (const float*)d_in[1], (const int*)d_in[2],
        (const float*)d_in[3], (const float*)d_in[4], (const float*)d_in[5],
        (const float*)d_in[6],
        (const float*)d_in[8], (const float*)d_in[10], (const float*)d_in[12],
        (const float*)d_in[14], (const float*)d_in[16], (const float*)d_in[18],
        (const float*)d_in[20], (const float*)d_in[22], (const float*)d_in[24],
        wbf, y1ws, (float*)d_out);
  } else {
    autoint_main<false><<<NSAMP, 256, 0, stream>>>(
        (const int*)d_in[0], (const float*)d_in[1], (const int*)d_in[2],
        (const float*)d_in[3], (const float*)d_in[4], (const float*)d_in[5],
        (const float*)d_in[6],
        (const float*)d_in[8], (const float*)d_in[10], (const float*)d_in[12],
        (const float*)d_in[14], (const float*)d_in[16], (const float*)d_in[18],
        (const float*)d_in[20], (const float*)d_in[22], (const float*)d_in[24],
        wbf, y1ws, (float*)d_out);
  }
}

// Round 9
// 346.885 us; speedup vs baseline: 1.3534x; 1.3534x over previous
//
#include <hip/hip_runtime.h>

// AutoInt fused: embedding gather -> 2x MHSA (32 fields, 4 heads x 32) -> logit.
// One block (256 thr, 4 waves) per sample; wave h = head h.
// R9 = R6 structure (single kernel, 18.4KB LDS overlay, exp-sum-via-MFMA
//     softmax, fused logit) with all matmuls as ONE 32x32x16 MFMA tile:
//     halves MFMA count and per-proj address math (mi/ni loops gone).
// 32x32 C/D layout [measured m74/m101]: col=lane&31, row=(reg&3)+8*(reg>>2)+4*(lane>>5)

#define NSAMP 8192
#define S_Y1 72    // layer1 input stride (shorts): 144B rows (16B-aligned)
#define S_Y2 136   // layer2 input stride (shorts): 272B rows (16B-aligned)
#define S_T 36     // 32x32 tile stride (shorts): 72B rows (8B-aligned, stride 18 words -> 2-way banks, free)

typedef __attribute__((ext_vector_type(8))) short bf8_t;   // 8 bf16 (4 VGPRs)
typedef __attribute__((ext_vector_type(16))) float f16v;   // 32x32 C/D

__device__ __forceinline__ short f2bf(float f) {
  unsigned u = __float_as_uint(f);
  u += 0x7fffu + ((u >> 16) & 1u);   // RNE
  return (short)(u >> 16);
}
__device__ __forceinline__ unsigned pack2(float a, float b) {
  return ((unsigned)(unsigned short)f2bf(a)) |
         (((unsigned)(unsigned short)f2bf(b)) << 16);
}
__device__ __forceinline__ float bf2f(short s) {
  return __uint_as_float(((unsigned)(unsigned short)s) << 16);
}
__device__ __forceinline__ f16v mfma32(bf8_t a, bf8_t b, f16v c) {
  return __builtin_amdgcn_mfma_f32_32x32x16_bf16(a, b, c, 0, 0, 0);
}

// C = y(32xD) * W(32xD)^T + bias : A=y fields (m), B=W rows (n). One 32x32 tile.
template<int D_IN>
__device__ __forceinline__ f16v proj32(const bf8_t (&af)[D_IN / 16],
                                       const short* __restrict__ W,
                                       const float* __restrict__ bias,
                                       int n0, int col, int h2) {
  constexpr int KS = D_IN / 16;
  float bb = bias[n0 + col];
  f16v acc;
#pragma unroll
  for (int i = 0; i < 16; ++i) acc[i] = bb;
#pragma unroll
  for (int kc = 0; kc < KS; ++kc) {
    bf8_t b = *(const bf8_t*)&W[(n0 + col) * D_IN + kc * 16 + h2 * 8];
    acc = mfma32(af[kc], b, acc);
  }
  return acc;
}

// One attention layer for this wave's head (R6 overlay/barrier structure).
template<int D_IN, int S_IN, bool FUSE>
__device__ float attn_layer(const short* yIn, short* yOut,
                            const short* __restrict__ Wq, const short* __restrict__ Wk,
                            const short* __restrict__ Wv, const short* __restrict__ Wr,
                            const float* __restrict__ bq, const float* __restrict__ bk,
                            const float* __restrict__ bvp, const float* __restrict__ br,
                            short* bQ, short* bK, const short* __restrict__ lwT) {
  constexpr int KS = D_IN / 16;
  const int lane = threadIdx.x & 63;
  const int col = lane & 31;
  const int h2 = lane >> 5;            // half-wave: k-subgroup / +4 rows in C
  const int head = threadIdx.x >> 6;
  const int n0 = head * 32;

  // A-fragments of yIn: A[m=col][k = kc*16 + h2*8 + j]
  bf8_t af[KS];
#pragma unroll
  for (int kc = 0; kc < KS; ++kc)
    af[kc] = *(const bf8_t*)&yIn[col * S_IN + kc * 16 + h2 * 8];
  __syncthreads();   // yIn (overlaid on scr) is now dead; scr writable

  // ---- Q -> bQ row-major
  {
    f16v q = proj32<D_IN>(af, Wq, bq, n0, col, h2);
#pragma unroll
    for (int reg = 0; reg < 16; ++reg) {
      int row = (reg & 3) + 8 * (reg >> 2) + 4 * h2;
      bQ[row * S_T + col] = f2bf(q[reg]);
    }
  }
  // ---- K -> bK row-major
  {
    f16v k = proj32<D_IN>(af, Wk, bk, n0, col, h2);
#pragma unroll
    for (int reg = 0; reg < 16; ++reg) {
      int row = (reg & 3) + 8 * (reg >> 2) + 4 * h2;
      bK[row * S_T + col] = f2bf(k[reg]);
    }
  }
  // ---- Res -> registers (C-layout, aligned with PV output)
  f16v res = proj32<D_IN>(af, Wr, br, n0, col, h2);

  // ---- scores = Q K^T (K-dim = 32 head dims -> 2 chunks)
  f16v z;
#pragma unroll
  for (int i = 0; i < 16; ++i) z[i] = 0.f;
#pragma unroll
  for (int kc = 0; kc < 2; ++kc) {
    bf8_t qa = *(const bf8_t*)&bQ[col * S_T + kc * 16 + h2 * 8];
    bf8_t kb = *(const bf8_t*)&bK[col * S_T + kc * 16 + h2 * 8];
    z = mfma32(qa, kb, z);
  }

  // ---- e = exp(z) unnormalized -> bQ (scores O(1), no max-sub needed)
#pragma unroll
  for (int reg = 0; reg < 16; ++reg) {
    int row = (reg & 3) + 8 * (reg >> 2) + 4 * h2;
    bQ[row * S_T + col] = f2bf(__expf(z[reg]));
  }

  // ---- V -> bK transposed: bK[i=col][f=row], packed short4 runs of 4 rows
  {
    f16v v = proj32<D_IN>(af, Wv, bvp, n0, col, h2);
#pragma unroll
    for (int g = 0; g < 4; ++g) {
      short4 pk;
      pk.x = f2bf(v[g * 4 + 0]); pk.y = f2bf(v[g * 4 + 1]);
      pk.z = f2bf(v[g * 4 + 2]); pk.w = f2bf(v[g * 4 + 3]);
      *(short4*)&bK[col * S_T + 8 * g + 4 * h2] = pk;
    }
  }

  // ---- PV (unnormalized) + row-sums via all-ones B-frag (K-dim = 32 fields)
  const short onebf = (short)0x3F80;
  bf8_t ones = {onebf, onebf, onebf, onebf, onebf, onebf, onebf, onebf};
  f16v pv, sums;
#pragma unroll
  for (int i = 0; i < 16; ++i) { pv[i] = 0.f; sums[i] = 0.f; }
#pragma unroll
  for (int kc = 0; kc < 2; ++kc) {
    bf8_t pa = *(const bf8_t*)&bQ[col * S_T + kc * 16 + h2 * 8];
    bf8_t vb = *(const bf8_t*)&bK[col * S_T + kc * 16 + h2 * 8];
    pv = mfma32(pa, vb, pv);
    sums = mfma32(pa, ones, sums);
  }

  // ---- O = PV/s + Res, relu; store (layer1) or fuse logit dot (layer2)
  float p = 0.f;
  if (FUSE) {
#pragma unroll
    for (int g = 0; g < 4; ++g) {
      short4 l4 = *(const short4*)&lwT[(n0 + col) * 32 + 8 * g + 4 * h2];
#pragma unroll
      for (int r = 0; r < 4; ++r) {
        int reg = g * 4 + r;
        float ov = fmaxf(fmaf(pv[reg], 1.f / sums[reg], res[reg]), 0.f);
        short lv = (r == 0) ? l4.x : (r == 1) ? l4.y : (r == 2) ? l4.z : l4.w;
        p += ov * bf2f(lv);
      }
    }
  } else {
    __syncthreads();   // all waves done reading scr; scr union writable as yOut
#pragma unroll
    for (int reg = 0; reg < 16; ++reg) {
      int row = (reg & 3) + 8 * (reg >> 2) + 4 * h2;
      yOut[row * S_Y2 + n0 + col] =
          f2bf(fmaxf(fmaf(pv[reg], 1.f / sums[reg], res[reg]), 0.f));
    }
  }
  return p;
}

__global__ __launch_bounds__(256, 4) void autoint_main(
    const int* __restrict__ onehot_i, const float* __restrict__ onehot_x,
    const int* __restrict__ mh_i, const float* __restrict__ mh_x,
    const float* __restrict__ ctns, const float* __restrict__ xx,
    const float* __restrict__ xy,
    const float* __restrict__ bq1, const float* __restrict__ bk1,
    const float* __restrict__ bv1, const float* __restrict__ br1,
    const float* __restrict__ bq2, const float* __restrict__ bk2,
    const float* __restrict__ bv2, const float* __restrict__ br2,
    const float* __restrict__ logitb, const short* __restrict__ wbf,
    float* __restrict__ out) {
  // scr union (18432 B) also hosts yA (4608 B) and yB (8704 B) at its base,
  // with barriers fencing the disjoint lifetimes.
  __shared__ __align__(16) short scr[4][2][32 * S_T];
  __shared__ float red[4];

  const int s = blockIdx.x;
  const int t = threadIdx.x;
  const int head = t >> 6;
  short* bQ = scr[head][0];
  short* bK = scr[head][1];
  short* yA = &scr[0][0][0];

  // ---- embedding build into yA [32][64] (bf16, 8B packed writes)
  for (int idx = t; idx < 320; idx += 256) {     // 20 onehot x 16 float4
    int f = idx >> 4, e4 = idx & 15;
    int row = onehot_i[s * 20 + f];
    float xw = onehot_x[s * 20 + f];
    float4 xv = *(const float4*)&xx[row * 64 + e4 * 4];
    uint2 w; w.x = pack2(xv.x * xw, xv.y * xw); w.y = pack2(xv.z * xw, xv.w * xw);
    *(uint2*)&yA[f * S_Y1 + e4 * 4] = w;
  }
  {                                               // 2 multihot x 16 float4, 8-way k-split
    int slot = t >> 3, ks = t & 7;
    int j = slot >> 4, e4 = slot & 15;
    const int* ip = &mh_i[(j * NSAMP + s) * 50];
    const float* xp = &mh_x[(j * NSAMP + s) * 50];
    float a0 = 0.f, a1 = 0.f, a2 = 0.f, a3 = 0.f;
    for (int k = ks; k < 50; k += 8) {
      float4 xv = *(const float4*)&xx[ip[k] * 64 + e4 * 4];
      float w = xp[k];
      a0 += xv.x * w; a1 += xv.y * w; a2 += xv.z * w; a3 += xv.w * w;
    }
#pragma unroll
    for (int d = 1; d < 8; d <<= 1) {
      a0 += __shfl_xor(a0, d); a1 += __shfl_xor(a1, d);
      a2 += __shfl_xor(a2, d); a3 += __shfl_xor(a3, d);
    }
    if (ks == 0) {
      uint2 w; w.x = pack2(a0, a1); w.y = pack2(a2, a3);
      *(uint2*)&yA[(20 + j) * S_Y1 + e4 * 4] = w;
    }
  }
  if (t < 160) {                                  // 10 ctns x 16 float4
    int ci = t >> 4, e4 = t & 15;
    float cv = ctns[s * 10 + ci];
    float4 xv = *(const float4*)&xy[ci * 64 + e4 * 4];
    uint2 w; w.x = pack2(cv * xv.x, cv * xv.y); w.y = pack2(cv * xv.z, cv * xv.w);
    *(uint2*)&yA[(22 + ci) * S_Y1 + e4 * 4] = w;
  }
  __syncthreads();

  attn_layer<64, S_Y1, false>(yA, yA,
      wbf + 0, wbf + 8192, wbf + 16384, wbf + 24576,
      bq1, bk1, bv1, br1, bQ, bK, nullptr);
  __syncthreads();   // yB (= yA region) fully written before layer2 frag load
  float p = attn_layer<128, S_Y2, true>(yA, nullptr,
      wbf + 32768, wbf + 49152, wbf + 65536, wbf + 81920,
      bq2, bk2, bv2, br2, bQ, bK, wbf + 98304);

  // ---- block reduce of logit partials, sigmoid
#pragma unroll
  for (int off = 32; off > 0; off >>= 1) p += __shfl_xor(p, off);
  if ((t & 63) == 0) red[head] = p;
  __syncthreads();
  if (t == 0) {
    float zz = red[0] + red[1] + red[2] + red[3] + logitb[0];
    out[s] = 1.f / (1.f + __expf(-zz));
  }
}

// fp32 -> bf16 weight conversion into ws:
// [0)QW1 [8192)KW1 [16384)VW1 [24576)RW1 [32768)QW2 [49152)KW2 [65536)VW2
// [81920)RW2 [98304)logitW TRANSPOSED [128][32]
__global__ void convert_w(const float* __restrict__ qw1, const float* __restrict__ kw1,
                          const float* __restrict__ vw1, const float* __restrict__ rw1,
                          const float* __restrict__ qw2, const float* __restrict__ kw2,
                          const float* __restrict__ vw2, const float* __restrict__ rw2,
                          const float* __restrict__ lw, short* __restrict__ outw) {
  int i = blockIdx.x * 256 + threadIdx.x;
  if (i >= 102400) return;
  float v;
  if (i < 32768) {
    int tsel = i >> 13, j = i & 8191;
    const float* src = tsel == 0 ? qw1 : tsel == 1 ? kw1 : tsel == 2 ? vw1 : rw1;
    v = src[j];
  } else if (i < 98304) {
    int k = i - 32768;
    int tsel = k >> 14, j = k & 16383;
    const float* src = tsel == 0 ? qw2 : tsel == 1 ? kw2 : tsel == 2 ? vw2 : rw2;
    v = src[j];
  } else {
    int j = i - 98304;                 // outw layout: lwT[col*32+row]
    v = lw[(j & 31) * 128 + (j >> 5)];
  }
  outw[i] = f2bf(v);
}

extern "C" void kernel_launch(void* const* d_in, const int* in_sizes, int n_in,
                              void* d_out, int out_size, void* d_ws, size_t ws_size,
                              hipStream_t stream) {
  short* wbf = (short*)d_ws;  // 204800 bytes used
  convert_w<<<400, 256, 0, stream>>>(
      (const float*)d_in[7], (const float*)d_in[9], (const float*)d_in[11],
      (const float*)d_in[13], (const float*)d_in[15], (const float*)d_in[17],
      (const float*)d_in[19], (const float*)d_in[21], (const float*)d_in[23], wbf);
  autoint_main<<<NSAMP, 256, 0, stream>>>(
      (const int*)d_in[0], (const float*)d_in[1], (const int*)d_in[2],
      (const float*)d_in[3], (const float*)d_in[4], (const float*)d_in[5],
      (const float*)d_in[6],
      (const float*)d_in[8], (const float*)d_in[10], (const float*)d_in[12],
      (const float*)d_in[14], (const float*)d_in[16], (const float*)d_in[18],
      (const float*)d_in[20], (const float*)d_in[22], (const float*)d_in[24],
      wbf, (float*)d_out);
}